// Round 4
// baseline (34.976 us; speedup 1.0000x reference)
//
#include <hip/hip_runtime.h>

#define THETA 2.0f
#define NRHO 2048
#define NOUT 2044   // NRHO - 4
#define RPB  4      // rows per block

typedef float floatx4 __attribute__((ext_vector_type(4)));

__global__ __launch_bounds__(256) void vprime_stencil_kernel(
    const float* __restrict__ rho,
    const float* __restrict__ v,
    float* __restrict__ out)
{
    const int t    = threadIdx.x;      // 0..255; thread handles outputs 8t..8t+7
    const int row0 = blockIdx.x * RPB;
    const bool full = (t < 255);       // t=255 has only 4 valid outputs

    floatx4 R0[RPB], R1[RPB], R2[RPB], V0[RPB], V1[RPB];

    // Phase 1: issue ALL loads for all RPB rows (deep per-thread MLP,
    // ~320B in flight per lane).
    #pragma unroll
    for (int rr = 0; rr < RPB; ++rr) {
        const size_t row = row0 + rr;
        const floatx4* r4 = reinterpret_cast<const floatx4*>(rho + row * NRHO);
        const floatx4* v4 = reinterpret_cast<const floatx4*>(v   + row * NOUT);
        R0[rr] = r4[2 * t];
        R1[rr] = r4[2 * t + 1];
        R2[rr] = full ? r4[2 * t + 2] : floatx4{0.f, 0.f, 0.f, 0.f};
        V0[rr] = v4[2 * t];
        V1[rr] = full ? v4[2 * t + 1] : floatx4{0.f, 0.f, 0.f, 0.f};
    }

    // Phase 2: compute + store per row.
    #pragma unroll
    for (int rr = 0; rr < RPB; ++rr) {
        const size_t row = row0 + rr;
        floatx4* o4 = reinterpret_cast<floatx4*>(out + row * NOUT);

        float x[12] = {R0[rr].x, R0[rr].y, R0[rr].z, R0[rr].w,
                       R1[rr].x, R1[rr].y, R1[rr].z, R1[rr].w,
                       R2[rr].x, R2[rr].y, R2[rr].z, R2[rr].w};

        // half-slopes hs(i) for i = 8t .. 8t+9 (tail thread's hs[6..9] use
        // zero-padded x — computed but never stored)
        float hs[10];
        #pragma unroll
        for (int i = 0; i < 10; ++i) {
            float a  = THETA * (x[i + 1] - x[i]);
            float b  = 0.5f  * (x[i + 2] - x[i]);
            float c  = THETA * (x[i + 2] - x[i + 1]);
            float mn = fminf(fminf(a, b), c);
            float mx = fmaxf(fmaxf(a, b), c);
            hs[i] = 0.5f * ((mn < 0.0f) ? fminf(mx, 0.0f) : mn);
        }

        float vf[8] = {V0[rr].x, V0[rr].y, V0[rr].z, V0[rr].w,
                       V1[rr].x, V1[rr].y, V1[rr].z, V1[rr].w};

        floatx4 res0, res1;
        #pragma unroll
        for (int m = 0; m < 8; ++m) {
            float rp = (x[m + 2] - x[m + 1]) + (hs[m + 1] - hs[m]);
            float rm = (x[m + 3] - x[m + 2]) - (hs[m + 2] - hs[m + 1]);
            float dr = (vf[m] < 0.0f) ? rm : rp;
            float r  = vf[m] * dr;
            if (m < 4) res0[m] = r; else res1[m - 4] = r;
        }

        o4[2 * t] = res0;
        if (full) o4[2 * t + 1] = res1;
    }
}

extern "C" void kernel_launch(void* const* d_in, const int* in_sizes, int n_in,
                              void* d_out, int out_size, void* d_ws, size_t ws_size,
                              hipStream_t stream) {
    const float* rho = (const float*)d_in[0];
    const float* v   = (const float*)d_in[1];
    float* out       = (float*)d_out;

    const int rows = in_sizes[0] / NRHO;   // 32*256 = 8192

    vprime_stencil_kernel<<<rows / RPB, 256, 0, stream>>>(rho, v, out);
}